// Round 8
// baseline (433.815 us; speedup 1.0000x reference)
//
#include <hip/hip_runtime.h>
#include <hip/hip_bf16.h>
#include <stdint.h>

typedef __bf16 bf16_t;
typedef __bf16 bf16x4 __attribute__((ext_vector_type(4)));
typedef __bf16 bf16x8 __attribute__((ext_vector_type(8)));
typedef float floatx4 __attribute__((ext_vector_type(4)));

#define MFMA_16x16x32_BF16(a, b, c) __builtin_amdgcn_mfma_f32_16x16x32_bf16((a), (b), (c), 0, 0, 0)

// Async 16B global->LDS copy. LDS dest is wave-uniform base + lane*16;
// global source address is per-lane (learn_hip m104/m108).
__device__ __forceinline__ void gload_lds16(const bf16_t* g, bf16_t* lds_base) {
  __builtin_amdgcn_global_load_lds(
      (const __attribute__((address_space(1))) void*)g,
      (__attribute__((address_space(3))) void*)lds_base, 16, 0, 0);
}

// ---------- fp32 -> bf16 elementwise convert (memory-bound, 16B loads) ----------
__global__ __launch_bounds__(256)
void f32_to_bf16_kernel(const float* __restrict__ in, bf16_t* __restrict__ out, int n8)
{
  for (int i = blockIdx.x * 256 + threadIdx.x; i < n8; i += gridDim.x * 256) {
    const float* p = in + (size_t)i * 8;
    floatx4 f0 = *(const floatx4*)p;
    floatx4 f1 = *(const floatx4*)(p + 4);
    bf16x8 r;
#pragma unroll
    for (int j = 0; j < 4; j++) { r[j] = (bf16_t)f0[j]; r[j + 4] = (bf16_t)f1[j]; }
    *(bf16x8*)(out + (size_t)i * 8) = r;
  }
}

// ===================== 256x256 pipelined counted-vmcnt GEMM =====================
// r8 = r7's read-ahead pipeline with the SYNC PROTOCOL FIXED (r7 raced):
// publication of a staged tile is  vmcnt(N) -> s_barrier  (each wave drains its
// OWN global_load_lds before the barrier; after the barrier all waves' data has
// landed). r7 had barrier->vmcnt which publishes nothing. Two barriers/tile:
//   #1 after Q11 (all reads of the buffer consumed by MFMAs => lgkm-drained)
//      -> safe to overwrite buffer with STAGE(kt+2)
//   #2 after vmcnt(8) -> publishes tile kt+1; its Q00 frags are then read in
//      P3's MFMA shadow.
// Staging math, T2 byte-swizzle (0 bank conflicts measured), T1 XCD swizzle,
// and both epilogues identical to the r6 passing kernel.
template <typename TOUT, bool BIAS>
__global__ __launch_bounds__(512, 1)
void gemm_bt256(const bf16_t* __restrict__ A, const bf16_t* __restrict__ B,
                const float* __restrict__ bias, TOUT* __restrict__ C,
                int M, int N, int K)
{
  __shared__ bf16_t S[65536];   // [Abuf0 16K][Abuf1 16K][Bbuf0 16K][Bbuf1 16K] elems
  const int t = threadIdx.x;
  const int lane = t & 63, wave = t >> 6;
  const int quad = lane >> 4, l15 = lane & 15;
  const int wm = wave >> 2, wn = wave & 3;

  // T1: bijective XCD swizzle (gridDim.x % 8 == 0 for all our launches)
  const int cpx = gridDim.x >> 3;
  const int obid = blockIdx.x;
  const int bid = (obid & 7) * cpx + (obid >> 3);
  const int nbx = N >> 8;
  const int bx = bid % nbx, by = bid / nbx;
  const int m0 = by * 256, n0 = bx * 256;

  // ---- staging: 4 A-loads + 4 B-loads per thread per K-tile ----
  uint32_t aoff[4], boff[4];
  bf16_t* asd[4]; bf16_t* bsd[4];
#pragma unroll
  for (int j = 0; j < 4; j++) {
    const uint32_t o = (uint32_t)(j * 512 + t) * 16u;
    const uint32_t u = o ^ (((o >> 7) & 7u) << 4);
    const uint32_t row = u >> 7, colb = u & 127u;
    aoff[j] = (uint32_t)(m0 + row) * (uint32_t)(K * 2) + colb;
    boff[j] = (uint32_t)(n0 + row) * (uint32_t)(K * 2) + colb;
    asd[j] = S + j * 4096 + wave * 512;
    bsd[j] = S + 32768 + j * 4096 + wave * 512;
  }

  // ---- ds_read bases (swizzled) ----
  const uint32_t sw = (uint32_t)((l15 & 7) << 4);
  const uint32_t ce0 = (((uint32_t)(quad * 16)) ^ sw) >> 1;
  const uint32_t ce1 = ce0 ^ 32u;
  const bf16_t* lraA0 = S + (wm * 128 + l15) * 64 + ce0;
  const bf16_t* lraA1 = S + (wm * 128 + l15) * 64 + ce1;
  const bf16_t* lraB0 = S + 32768 + (wn * 64 + l15) * 64 + ce0;
  const bf16_t* lraB1 = S + 32768 + (wn * 64 + l15) * 64 + ce1;

  floatx4 acc[8][4] = {};
  const int NT = K >> 6;   // even (K=1024 -> 16)

#define STAGE_TILE(kt, bo_) do {                                              \
    const uint32_t kadv_ = (uint32_t)((kt) * 128);                            \
    _Pragma("unroll")                                                         \
    for (int j = 0; j < 4; j++)                                               \
      gload_lds16((const bf16_t*)((const char*)A + aoff[j] + kadv_), asd[j] + (bo_)); \
    _Pragma("unroll")                                                         \
    for (int j = 0; j < 4; j++)                                               \
      gload_lds16((const bf16_t*)((const char*)B + boff[j] + kadv_), bsd[j] + (bo_)); \
  } while (0)

#define FENCE() __builtin_amdgcn_sched_barrier(0)

  bf16x8 afA[4][2];   // current tile A-h0 (P0,P1)
  bf16x8 afB[4][2];   // current tile A-h1 (P2,P3)
  bf16x8 bA[2][2];    // B-h0 of EVEN tiles (P0,P3)
  bf16x8 bAn[2][2];   // B-h0 of ODD tiles
  bf16x8 bB[2][2];    // current tile B-h1 (P1,P2)

  // prologue: stage tiles 0,1; PUBLISH tile 0 (vmcnt -> barrier); read Q00 frags
  STAGE_TILE(0, 0);
  STAGE_TILE(1, 16384);
  asm volatile("s_waitcnt vmcnt(8)" ::: "memory");   // my tile-0 loads landed
  __builtin_amdgcn_s_barrier();                      // => everyone's landed
  FENCE();
#pragma unroll
  for (int mi = 0; mi < 4; mi++) {
    afA[mi][0] = *(const bf16x8*)(lraA0 + mi * 1024);
    afA[mi][1] = *(const bf16x8*)(lraA1 + mi * 1024);
  }
#pragma unroll
  for (int ni = 0; ni < 2; ni++) {
    bA[ni][0] = *(const bf16x8*)(lraB0 + ni * 1024);
    bA[ni][1] = *(const bf16x8*)(lraB1 + ni * 1024);
  }

  for (int i = 0; ; i++) {
    const int e = 2 * i;
    // ================= even tile e, buffer 0 =================
    // P0: Q00 (afA x bA) ; read-ahead bB
    __builtin_amdgcn_s_setprio(1);
#pragma unroll
    for (int mi = 0; mi < 4; mi++)
#pragma unroll
      for (int ni = 0; ni < 2; ni++) {
        acc[mi][ni] = MFMA_16x16x32_BF16(afA[mi][0], bA[ni][0], acc[mi][ni]);
        acc[mi][ni] = MFMA_16x16x32_BF16(afA[mi][1], bA[ni][1], acc[mi][ni]);
      }
    __builtin_amdgcn_s_setprio(0);
#pragma unroll
    for (int ni = 0; ni < 2; ni++) {
      bB[ni][0] = *(const bf16x8*)(lraB0 + (ni + 2) * 1024);
      bB[ni][1] = *(const bf16x8*)(lraB1 + (ni + 2) * 1024);
    }
    // P1: Q01 (afA x bB) ; read-ahead afB
    __builtin_amdgcn_s_setprio(1);
#pragma unroll
    for (int mi = 0; mi < 4; mi++)
#pragma unroll
      for (int ni = 0; ni < 2; ni++) {
        acc[mi][ni + 2] = MFMA_16x16x32_BF16(afA[mi][0], bB[ni][0], acc[mi][ni + 2]);
        acc[mi][ni + 2] = MFMA_16x16x32_BF16(afA[mi][1], bB[ni][1], acc[mi][ni + 2]);
      }
    __builtin_amdgcn_s_setprio(0);
#pragma unroll
    for (int mi = 0; mi < 4; mi++) {
      afB[mi][0] = *(const bf16x8*)(lraA0 + (mi + 4) * 1024);
      afB[mi][1] = *(const bf16x8*)(lraA1 + (mi + 4) * 1024);
    }
    // P2: Q11 (afB x bB) — consumes the last reads of buf0 => lgkm drained
    __builtin_amdgcn_s_setprio(1);
#pragma unroll
    for (int mi = 0; mi < 4; mi++)
#pragma unroll
      for (int ni = 0; ni < 2; ni++) {
        acc[mi + 4][ni + 2] = MFMA_16x16x32_BF16(afB[mi][0], bB[ni][0], acc[mi + 4][ni + 2]);
        acc[mi + 4][ni + 2] = MFMA_16x16x32_BF16(afB[mi][1], bB[ni][1], acc[mi + 4][ni + 2]);
      }
    __builtin_amdgcn_s_setprio(0);
    FENCE();
    __builtin_amdgcn_s_barrier();       // #1: all waves done READING buf0
    FENCE();
    if (e + 2 < NT) {
      STAGE_TILE(e + 2, 0);             // overwrite buf0
      asm volatile("s_waitcnt vmcnt(8)" ::: "memory");   // my tile e+1 loads landed
    } else {
      asm volatile("s_waitcnt vmcnt(0)" ::: "memory");
    }
    __builtin_amdgcn_s_barrier();       // #2: tile e+1 PUBLISHED
    FENCE();
    // read-ahead odd tile's Q00 frags (buf1) under P3's MFMA
#pragma unroll
    for (int mi = 0; mi < 4; mi++) {
      afA[mi][0] = *(const bf16x8*)(lraA0 + 16384 + mi * 1024);
      afA[mi][1] = *(const bf16x8*)(lraA1 + 16384 + mi * 1024);
    }
#pragma unroll
    for (int ni = 0; ni < 2; ni++) {
      bAn[ni][0] = *(const bf16x8*)(lraB0 + 16384 + ni * 1024);
      bAn[ni][1] = *(const bf16x8*)(lraB1 + 16384 + ni * 1024);
    }
    // P3: Q10 (afB x bA) — register-only
    __builtin_amdgcn_s_setprio(1);
#pragma unroll
    for (int mi = 0; mi < 4; mi++)
#pragma unroll
      for (int ni = 0; ni < 2; ni++) {
        acc[mi + 4][ni] = MFMA_16x16x32_BF16(afB[mi][0], bA[ni][0], acc[mi + 4][ni]);
        acc[mi + 4][ni] = MFMA_16x16x32_BF16(afB[mi][1], bA[ni][1], acc[mi + 4][ni]);
      }
    __builtin_amdgcn_s_setprio(0);

    // ================= odd tile e+1, buffer 1 =================
    // P0: Q00 (afA x bAn) ; read-ahead bB (buf1)
    __builtin_amdgcn_s_setprio(1);
#pragma unroll
    for (int mi = 0; mi < 4; mi++)
#pragma unroll
      for (int ni = 0; ni < 2; ni++) {
        acc[mi][ni] = MFMA_16x16x32_BF16(afA[mi][0], bAn[ni][0], acc[mi][ni]);
        acc[mi][ni] = MFMA_16x16x32_BF16(afA[mi][1], bAn[ni][1], acc[mi][ni]);
      }
    __builtin_amdgcn_s_setprio(0);
#pragma unroll
    for (int ni = 0; ni < 2; ni++) {
      bB[ni][0] = *(const bf16x8*)(lraB0 + 16384 + (ni + 2) * 1024);
      bB[ni][1] = *(const bf16x8*)(lraB1 + 16384 + (ni + 2) * 1024);
    }
    // P1: Q01 ; read-ahead afB (buf1)
    __builtin_amdgcn_s_setprio(1);
#pragma unroll
    for (int mi = 0; mi < 4; mi++)
#pragma unroll
      for (int ni = 0; ni < 2; ni++) {
        acc[mi][ni + 2] = MFMA_16x16x32_BF16(afA[mi][0], bB[ni][0], acc[mi][ni + 2]);
        acc[mi][ni + 2] = MFMA_16x16x32_BF16(afA[mi][1], bB[ni][1], acc[mi][ni + 2]);
      }
    __builtin_amdgcn_s_setprio(0);
#pragma unroll
    for (int mi = 0; mi < 4; mi++) {
      afB[mi][0] = *(const bf16x8*)(lraA0 + 16384 + (mi + 4) * 1024);
      afB[mi][1] = *(const bf16x8*)(lraA1 + 16384 + (mi + 4) * 1024);
    }
    // P2: Q11
    __builtin_amdgcn_s_setprio(1);
#pragma unroll
    for (int mi = 0; mi < 4; mi++)
#pragma unroll
      for (int ni = 0; ni < 2; ni++) {
        acc[mi + 4][ni + 2] = MFMA_16x16x32_BF16(afB[mi][0], bB[ni][0], acc[mi + 4][ni + 2]);
        acc[mi + 4][ni + 2] = MFMA_16x16x32_BF16(afB[mi][1], bB[ni][1], acc[mi + 4][ni + 2]);
      }
    __builtin_amdgcn_s_setprio(0);
    FENCE();
    __builtin_amdgcn_s_barrier();       // #1: all waves done READING buf1
    FENCE();
    const bool more = (e + 2) < NT;
    if (e + 3 < NT) {
      STAGE_TILE(e + 3, 16384);
      asm volatile("s_waitcnt vmcnt(8)" ::: "memory");   // tile e+2's loads landed
    } else if (more) {
      asm volatile("s_waitcnt vmcnt(0)" ::: "memory");
    }
    if (more) {
      __builtin_amdgcn_s_barrier();     // #2: tile e+2 PUBLISHED
      FENCE();
#pragma unroll
      for (int mi = 0; mi < 4; mi++) {
        afA[mi][0] = *(const bf16x8*)(lraA0 + mi * 1024);
        afA[mi][1] = *(const bf16x8*)(lraA1 + mi * 1024);
      }
#pragma unroll
      for (int ni = 0; ni < 2; ni++) {
        bA[ni][0] = *(const bf16x8*)(lraB0 + ni * 1024);
        bA[ni][1] = *(const bf16x8*)(lraB1 + ni * 1024);
      }
    }
    // P3: Q10 (afB x bAn) — register-only
    __builtin_amdgcn_s_setprio(1);
#pragma unroll
    for (int mi = 0; mi < 4; mi++)
#pragma unroll
      for (int ni = 0; ni < 2; ni++) {
        acc[mi + 4][ni] = MFMA_16x16x32_BF16(afB[mi][0], bAn[ni][0], acc[mi + 4][ni]);
        acc[mi + 4][ni] = MFMA_16x16x32_BF16(afB[mi][1], bAn[ni][1], acc[mi + 4][ni]);
      }
    __builtin_amdgcn_s_setprio(0);
    if (!more) break;
  }
#undef STAGE_TILE
#undef FENCE

  if constexpr (sizeof(TOUT) == 2) {
    // bf16 output: LDS re-layout per wave -> 128B-coalesced b128 stores.
    __syncthreads();                       // all waves done with S main-loop reads
    bf16_t* Sw = S + wave * 1024;          // private 16x64 bf16 tile (2 KB/wave)
#pragma unroll
    for (int mi = 0; mi < 8; mi++) {
#pragma unroll
      for (int ni = 0; ni < 4; ni++) {
        const int col = ((ni ^ quad) & 3) * 16 + l15;   // XOR-swizzle 16-col groups by quad
        const float bv = BIAS ? bias[n0 + wn * 64 + ni * 16 + l15] : 0.0f;
#pragma unroll
        for (int r = 0; r < 4; r++)
          Sw[(quad * 4 + r) * 64 + col] = (bf16_t)(acc[mi][ni][r] + bv);
      }
      // in-wave RAW on LDS: compiler inserts lgkmcnt waits
#pragma unroll
      for (int c = 0; c < 2; c++) {
        const int idx = c * 64 + lane;
        const int row = idx >> 3, cg = idx & 7;
        const int scol = (cg * 8) ^ (((row >> 2) & 3) << 4);   // inverse swizzle
        bf16x8 vrow = *(const bf16x8*)(Sw + row * 64 + scol);
        bf16_t* dst = (bf16_t*)C + (size_t)(m0 + wm * 128 + mi * 16 + row) * N
                      + (n0 + wn * 64 + cg * 8);
        *(bf16x8*)dst = vrow;
      }
    }
  } else {
    // fp32 output: 64B-per-quad chunks already coalesce acceptably.
#pragma unroll
    for (int ni = 0; ni < 4; ni++) {
      const int col = n0 + wn * 64 + ni * 16 + l15;
      const float bv = BIAS ? bias[col] : 0.0f;
#pragma unroll
      for (int mi = 0; mi < 8; mi++) {
        const size_t rbase = (size_t)(m0 + wm * 128 + mi * 16 + quad * 4) * N + col;
#pragma unroll
        for (int r = 0; r < 4; r++)
          C[rbase + (size_t)r * N] = (TOUT)(acc[mi][ni][r] + bv);
      }
    }
  }
}

// Flash-style blocked attention (unchanged from passing r6 version).
__global__ __launch_bounds__(256)
void attn_kernel(const bf16_t* __restrict__ qkv, bf16_t* __restrict__ out)
{
  constexpr int VS = 72;
  __shared__ bf16_t Ks[64 * VS];
  __shared__ bf16_t Vt[64 * VS];
  __shared__ bf16_t Ps[4][16 * VS];

  const int h     = blockIdx.x & 15;
  const int qtile = blockIdx.x >> 4;

  const int t = threadIdx.x;
  const int wave = t >> 6, lane = t & 63;
  const int quad = lane >> 4, l15 = lane & 15;

  const int qrow0 = qtile * 256 + wave * 64;
  const int krow0 = (qtile >> 1) * 512;
  const int qcol = h * 64;
  const int kcol = 1024 + h * 64;
  const int vcol = 2048 + h * 64;

  bf16x8 qf[4][2];
#pragma unroll
  for (int mi = 0; mi < 4; mi++)
#pragma unroll
    for (int kb = 0; kb < 2; kb++)
      qf[mi][kb] = *(const bf16x8*)(qkv + (size_t)(qrow0 + mi * 16 + l15) * 3072 + qcol + kb * 32 + quad * 8);

  floatx4 o[4][4] = {};
  float plsum[4] = {};

  const float SCL = 0.125f * 1.44269504088896f;

  const bf16_t* kg0 = qkv + (size_t)(krow0 + (t >> 3)) * 3072 + kcol + (t & 7) * 8;
  const bf16_t* kg1 = qkv + (size_t)(krow0 + 32 + (t >> 3)) * 3072 + kcol + (t & 7) * 8;
  const bf16_t* vg0 = qkv + (size_t)(krow0 + (t & 63)) * 3072 + vcol + (t >> 6) * 8;
  const bf16_t* vg1 = qkv + (size_t)(krow0 + (t & 63)) * 3072 + vcol + ((t >> 6) + 4) * 8;
  bf16_t* ksd0 = Ks + (t >> 3) * VS + (t & 7) * 8;
  bf16_t* ksd1 = Ks + ((t >> 3) + 32) * VS + (t & 7) * 8;
  bf16_t* vtd0 = Vt + (t >> 6) * 8 * VS + (t & 63);
  bf16_t* vtd1 = Vt + ((t >> 6) + 4) * 8 * VS + (t & 63);

  bf16x8 kreg0 = *(const bf16x8*)kg0;
  bf16x8 kreg1 = *(const bf16x8*)kg1;
  bf16x8 vreg0 = *(const bf16x8*)vg0;
  bf16x8 vreg1 = *(const bf16x8*)vg1;

  for (int it = 0; it < 8; it++) {
    __syncthreads();
    *(bf16x8*)ksd0 = kreg0;
    *(bf16x8*)ksd1 = kreg1;
#pragma unroll
    for (int j = 0; j < 8; j++) { vtd0[j * VS] = vreg0[j]; vtd1[j * VS] = vreg1[j]; }
    __syncthreads();

    if (it < 7) {
      const size_t off = (size_t)(it + 1) * 64 * 3072;
      kreg0 = *(const bf16x8*)(kg0 + off);
      kreg1 = *(const bf16x8*)(kg1 + off);
      vreg0 = *(const bf16x8*)(vg0 + off);
      vreg1 = *(const bf16x8*)(vg1 + off);
    }

    bf16x8 kf[4][2], vf[4][2];
#pragma unroll
    for (int ni = 0; ni < 4; ni++)
#pragma unroll
      for (int kb = 0; kb < 2; kb++) {
        kf[ni][kb] = *(const bf16x8*)(Ks + (ni * 16 + l15) * VS + kb * 32 + quad * 8);
        vf[ni][kb] = *(const bf16x8*)(Vt + (ni * 16 + l15) * VS + kb * 32 + quad * 8);
      }

#pragma unroll
    for (int mi = 0; mi < 4; mi++) {
      floatx4 s[4] = {};
      __builtin_amdgcn_s_setprio(1);
#pragma unroll
      for (int ni = 0; ni < 4; ni++) {
        s[ni] = MFMA_16x16x32_BF16(kf[ni][0], qf[mi][0], s[ni]);
        s[ni] = MFMA_16x16x32_BF16(kf[ni][1], qf[mi][1], s[ni]);
      }
      __builtin_amdgcn_s_setprio(0);
      float ps = 0.0f;
#pragma unroll
      for (int ni = 0; ni < 4; ni++) {
        bf16x4 w;
#pragma unroll
        for (int r = 0; r < 4; r++) {
          const float p = exp2f(s[ni][r] * SCL);
          ps += p;
          w[r] = (bf16_t)p;
        }
        *(bf16x4*)(Ps[wave] + l15 * VS + ni * 16 + quad * 4) = w;
      }
      plsum[mi] += ps;
      bf16x8 pf0 = *(const bf16x8*)(Ps[wave] + l15 * VS + quad * 8);
      bf16x8 pf1 = *(const bf16x8*)(Ps[wave] + l15 * VS + 32 + quad * 8);
      __builtin_amdgcn_s_setprio(1);
#pragma unroll
      for (int ni = 0; ni < 4; ni++) {
        o[mi][ni] = MFMA_16x16x32_BF16(pf0, vf[ni][0], o[mi][ni]);
        o[mi][ni] = MFMA_16x16x32_BF16(pf1, vf[ni][1], o[mi][ni]);
      }
      __builtin_amdgcn_s_setprio(0);
    }
  }

#pragma unroll
  for (int mi = 0; mi < 4; mi++) {
    float tot = plsum[mi];
    tot += __shfl_xor(tot, 16, 64);
    tot += __shfl_xor(tot, 32, 64);
    const float inv = 1.0f / tot;
#pragma unroll
    for (int r = 0; r < 4; r++) {
      const float invr = __shfl(inv, quad * 4 + r, 16);
      const size_t rbase = (size_t)(qrow0 + mi * 16 + quad * 4 + r) * 1024 + h * 64 + l15;
#pragma unroll
      for (int ni = 0; ni < 4; ni++)
        out[rbase + ni * 16] = (bf16_t)(o[mi][ni][r] * invr);
    }
  }
}

extern "C" void kernel_launch(void* const* d_in, const int* in_sizes, int n_in,
                              void* d_out, int out_size, void* d_ws, size_t ws_size,
                              hipStream_t stream)
{
  const float* x     = (const float*)d_in[0];   // [4,4096,1024]
  const float* w_qkv = (const float*)d_in[1];   // [3072,1024]
  const float* w_out = (const float*)d_in[2];   // [1024,1024]
  const float* b_out = (const float*)d_in[3];   // [1024]
  float* out = (float*)d_out;                   // [4,4096,1024] fp32

  const size_t WQ = (size_t)3072 * 1024, WO = (size_t)1024 * 1024;
  bf16_t* wq_b = (bf16_t*)d_ws;
  bf16_t* wo_b = wq_b + WQ;

  int rows = 16384;   // 10240 B/row of chunk buffers
  while ((size_t)rows * 10240 + (WQ + WO) * 2 > ws_size && rows > 512) rows >>= 1;
  const int nchunk = 16384 / rows;

  bf16_t* qkv_c = wo_b + WO;
  bf16_t* att_c = qkv_c + (size_t)rows * 3072;
  bf16_t* x_c   = att_c + (size_t)rows * 1024;

  f32_to_bf16_kernel<<<1536, 256, 0, stream>>>(w_qkv, wq_b, (int)(WQ / 8));
  f32_to_bf16_kernel<<<512, 256, 0, stream>>>(w_out, wo_b, (int)(WO / 8));

  for (int c = 0; c < nchunk; c++) {
    const float* xc = x + (size_t)c * rows * 1024;
    float* outc = out + (size_t)c * rows * 1024;
    // 0) x chunk -> bf16
    f32_to_bf16_kernel<<<2048, 256, 0, stream>>>(xc, x_c, rows * 128);
    // 1) QKV projection (bf16 x bf16 -> bf16): grid = 12*(rows/256), %8==0
    gemm_bt256<bf16_t, false><<<dim3((3072 / 256) * (rows / 256)), 512, 0, stream>>>(
        x_c, wq_b, nullptr, qkv_c, rows, 3072, 1024);
    // 2) blocked attention
    attn_kernel<<<dim3(16 * (rows / 256)), 256, 0, stream>>>(qkv_c, att_c);
    // 3) output projection + bias: grid = 4*(rows/256), %8==0
    gemm_bt256<float, true><<<dim3((1024 / 256) * (rows / 256)), 512, 0, stream>>>(
        att_c, wo_b, b_out, outc, rows, 1024, 1024);
  }
}

// Round 9
// 357.021 us; speedup vs baseline: 1.2151x; 1.2151x over previous
//
#include <hip/hip_runtime.h>
#include <hip/hip_bf16.h>
#include <stdint.h>

typedef __bf16 bf16_t;
typedef __bf16 bf16x4 __attribute__((ext_vector_type(4)));
typedef __bf16 bf16x8 __attribute__((ext_vector_type(8)));
typedef float floatx4 __attribute__((ext_vector_type(4)));

#define MFMA_16x16x32_BF16(a, b, c) __builtin_amdgcn_mfma_f32_16x16x32_bf16((a), (b), (c), 0, 0, 0)

// Async 16B global->LDS copy. LDS dest is wave-uniform base + lane*16;
// global source address is per-lane (learn_hip m104/m108).
__device__ __forceinline__ void gload_lds16(const bf16_t* g, bf16_t* lds_base) {
  __builtin_amdgcn_global_load_lds(
      (const __attribute__((address_space(1))) void*)g,
      (__attribute__((address_space(3))) void*)lds_base, 16, 0, 0);
}

// ---------- fp32 -> bf16 elementwise convert (memory-bound, 16B loads) ----------
__global__ __launch_bounds__(256)
void f32_to_bf16_kernel(const float* __restrict__ in, bf16_t* __restrict__ out, int n8)
{
  for (int i = blockIdx.x * 256 + threadIdx.x; i < n8; i += gridDim.x * 256) {
    const float* p = in + (size_t)i * 8;
    floatx4 f0 = *(const floatx4*)p;
    floatx4 f1 = *(const floatx4*)(p + 4);
    bf16x8 r;
#pragma unroll
    for (int j = 0; j < 4; j++) { r[j] = (bf16_t)f0[j]; r[j + 4] = (bf16_t)f1[j]; }
    *(bf16x8*)(out + (size_t)i * 8) = r;
  }
}

// ===================== 256x256 counted-vmcnt GEMM (r6 verbatim) =====================
// r8 post-mortem: read-ahead pipelining regressed this 1-block/CU kernel
// (spill traffic +48MB, all-wave stall between barriers). This r6 schedule —
// vmcnt(8)+barrier at loop top, inline phase reads, stage between barriers —
// is the verified optimum for the 4-phase structure: 107us, MfmaUtil 40%,
// 0 bank conflicts, no spills.
template <typename TOUT, bool BIAS>
__global__ __launch_bounds__(512, 1)
void gemm_bt256(const bf16_t* __restrict__ A, const bf16_t* __restrict__ B,
                const float* __restrict__ bias, TOUT* __restrict__ C,
                int M, int N, int K)
{
  __shared__ bf16_t S[65536];   // [Abuf0 16K][Abuf1 16K][Bbuf0 16K][Bbuf1 16K] elems
  const int t = threadIdx.x;
  const int lane = t & 63, wave = t >> 6;
  const int quad = lane >> 4, l15 = lane & 15;
  const int wm = wave >> 2, wn = wave & 3;

  // T1: bijective XCD swizzle (gridDim.x % 8 == 0 for all our launches)
  const int cpx = gridDim.x >> 3;
  const int obid = blockIdx.x;
  const int bid = (obid & 7) * cpx + (obid >> 3);
  const int nbx = N >> 8;
  const int bx = bid % nbx, by = bid / nbx;
  const int m0 = by * 256, n0 = bx * 256;

  // ---- staging: 4 A-loads + 4 B-loads per thread per K-tile ----
  uint32_t aoff[4], boff[4];
  bf16_t* asd[4]; bf16_t* bsd[4];
#pragma unroll
  for (int j = 0; j < 4; j++) {
    const uint32_t o = (uint32_t)(j * 512 + t) * 16u;
    const uint32_t u = o ^ (((o >> 7) & 7u) << 4);
    const uint32_t row = u >> 7, colb = u & 127u;
    aoff[j] = (uint32_t)(m0 + row) * (uint32_t)(K * 2) + colb;
    boff[j] = (uint32_t)(n0 + row) * (uint32_t)(K * 2) + colb;
    asd[j] = S + j * 4096 + wave * 512;
    bsd[j] = S + 32768 + j * 4096 + wave * 512;
  }

  // ---- ds_read bases (swizzled) ----
  const uint32_t sw = (uint32_t)((l15 & 7) << 4);
  const uint32_t ce0 = (((uint32_t)(quad * 16)) ^ sw) >> 1;
  const uint32_t ce1 = ce0 ^ 32u;
  const bf16_t* lraA0 = S + (wm * 128 + l15) * 64 + ce0;
  const bf16_t* lraA1 = S + (wm * 128 + l15) * 64 + ce1;
  const bf16_t* lraB0 = S + 32768 + (wn * 64 + l15) * 64 + ce0;
  const bf16_t* lraB1 = S + 32768 + (wn * 64 + l15) * 64 + ce1;

  floatx4 acc[8][4] = {};

  const int NT = K >> 6;
#pragma unroll
  for (int j = 0; j < 4; j++) gload_lds16((const bf16_t*)((const char*)A + aoff[j]), asd[j]);
#pragma unroll
  for (int j = 0; j < 4; j++) gload_lds16((const bf16_t*)((const char*)B + boff[j]), bsd[j]);
#pragma unroll
  for (int j = 0; j < 4; j++) gload_lds16((const bf16_t*)((const char*)A + aoff[j] + 128), asd[j] + 16384);
#pragma unroll
  for (int j = 0; j < 4; j++) gload_lds16((const bf16_t*)((const char*)B + boff[j] + 128), bsd[j] + 16384);

  for (int kt = 0; kt < NT; kt++) {
    const int bo = (kt & 1) * 16384;
    if (kt < NT - 1) asm volatile("s_waitcnt vmcnt(8)" ::: "memory");
    else             asm volatile("s_waitcnt vmcnt(0)" ::: "memory");
    __builtin_amdgcn_s_barrier();
    __builtin_amdgcn_sched_barrier(0);

    bf16x8 af[4][2], bA[2][2], bB[2][2];
    // ---- P0 ----
#pragma unroll
    for (int mi = 0; mi < 4; mi++) {
      af[mi][0] = *(const bf16x8*)(lraA0 + bo + mi * 1024);
      af[mi][1] = *(const bf16x8*)(lraA1 + bo + mi * 1024);
    }
#pragma unroll
    for (int ni = 0; ni < 2; ni++) {
      bA[ni][0] = *(const bf16x8*)(lraB0 + bo + ni * 1024);
      bA[ni][1] = *(const bf16x8*)(lraB1 + bo + ni * 1024);
    }
    __builtin_amdgcn_s_setprio(1);
#pragma unroll
    for (int mi = 0; mi < 4; mi++)
#pragma unroll
      for (int ni = 0; ni < 2; ni++) {
        acc[mi][ni] = MFMA_16x16x32_BF16(af[mi][0], bA[ni][0], acc[mi][ni]);
        acc[mi][ni] = MFMA_16x16x32_BF16(af[mi][1], bA[ni][1], acc[mi][ni]);
      }
    __builtin_amdgcn_s_setprio(0);
    // ---- P1 ----
#pragma unroll
    for (int ni = 0; ni < 2; ni++) {
      bB[ni][0] = *(const bf16x8*)(lraB0 + bo + (ni + 2) * 1024);
      bB[ni][1] = *(const bf16x8*)(lraB1 + bo + (ni + 2) * 1024);
    }
    __builtin_amdgcn_s_setprio(1);
#pragma unroll
    for (int mi = 0; mi < 4; mi++)
#pragma unroll
      for (int ni = 0; ni < 2; ni++) {
        acc[mi][ni + 2] = MFMA_16x16x32_BF16(af[mi][0], bB[ni][0], acc[mi][ni + 2]);
        acc[mi][ni + 2] = MFMA_16x16x32_BF16(af[mi][1], bB[ni][1], acc[mi][ni + 2]);
      }
    __builtin_amdgcn_s_setprio(0);
    // ---- P2 ----
#pragma unroll
    for (int mi = 0; mi < 4; mi++) {
      af[mi][0] = *(const bf16x8*)(lraA0 + bo + (mi + 4) * 1024);
      af[mi][1] = *(const bf16x8*)(lraA1 + bo + (mi + 4) * 1024);
    }
    __builtin_amdgcn_s_setprio(1);
#pragma unroll
    for (int mi = 0; mi < 4; mi++)
#pragma unroll
      for (int ni = 0; ni < 2; ni++) {
        acc[mi + 4][ni + 2] = MFMA_16x16x32_BF16(af[mi][0], bB[ni][0], acc[mi + 4][ni + 2]);
        acc[mi + 4][ni + 2] = MFMA_16x16x32_BF16(af[mi][1], bB[ni][1], acc[mi + 4][ni + 2]);
      }
    __builtin_amdgcn_s_setprio(0);
    __builtin_amdgcn_sched_barrier(0);
    __builtin_amdgcn_s_barrier();
    __builtin_amdgcn_sched_barrier(0);
    if (kt + 2 < NT) {
      const uint32_t kadv = (uint32_t)((kt + 2) * 128);
#pragma unroll
      for (int j = 0; j < 4; j++)
        gload_lds16((const bf16_t*)((const char*)A + aoff[j] + kadv), asd[j] + bo);
#pragma unroll
      for (int j = 0; j < 4; j++)
        gload_lds16((const bf16_t*)((const char*)B + boff[j] + kadv), bsd[j] + bo);
    }
    // ---- P3 ----
    __builtin_amdgcn_s_setprio(1);
#pragma unroll
    for (int mi = 0; mi < 4; mi++)
#pragma unroll
      for (int ni = 0; ni < 2; ni++) {
        acc[mi + 4][ni] = MFMA_16x16x32_BF16(af[mi][0], bA[ni][0], acc[mi + 4][ni]);
        acc[mi + 4][ni] = MFMA_16x16x32_BF16(af[mi][1], bA[ni][1], acc[mi + 4][ni]);
      }
    __builtin_amdgcn_s_setprio(0);
  }

  if constexpr (sizeof(TOUT) == 2) {
    // bf16 output: LDS re-layout per wave -> 128B-coalesced b128 stores.
    __syncthreads();                       // all waves done with S main-loop reads
    bf16_t* Sw = S + wave * 1024;          // private 16x64 bf16 tile (2 KB/wave)
#pragma unroll
    for (int mi = 0; mi < 8; mi++) {
#pragma unroll
      for (int ni = 0; ni < 4; ni++) {
        const int col = ((ni ^ quad) & 3) * 16 + l15;   // XOR-swizzle 16-col groups by quad
        const float bv = BIAS ? bias[n0 + wn * 64 + ni * 16 + l15] : 0.0f;
#pragma unroll
        for (int r = 0; r < 4; r++)
          Sw[(quad * 4 + r) * 64 + col] = (bf16_t)(acc[mi][ni][r] + bv);
      }
      // in-wave RAW on LDS: compiler inserts lgkmcnt waits
#pragma unroll
      for (int c = 0; c < 2; c++) {
        const int idx = c * 64 + lane;
        const int row = idx >> 3, cg = idx & 7;
        const int scol = (cg * 8) ^ (((row >> 2) & 3) << 4);   // inverse swizzle
        bf16x8 vrow = *(const bf16x8*)(Sw + row * 64 + scol);
        bf16_t* dst = (bf16_t*)C + (size_t)(m0 + wm * 128 + mi * 16 + row) * N
                      + (n0 + wn * 64 + cg * 8);
        *(bf16x8*)dst = vrow;
      }
    }
  } else {
    // fp32 output: 64B-per-quad chunks already coalesce acceptably.
#pragma unroll
    for (int ni = 0; ni < 4; ni++) {
      const int col = n0 + wn * 64 + ni * 16 + l15;
      const float bv = BIAS ? bias[col] : 0.0f;
#pragma unroll
      for (int mi = 0; mi < 8; mi++) {
        const size_t rbase = (size_t)(m0 + wm * 128 + mi * 16 + quad * 4) * N + col;
#pragma unroll
        for (int r = 0; r < 4; r++)
          C[rbase + (size_t)r * N] = (TOUT)(acc[mi][ni][r] + bv);
      }
    }
  }
}

// Flash-style blocked attention.
// r9: single-barrier double-buffered K/V staging. Per iter: the one
// __syncthreads at the top publishes buf[p] (written at the END of the
// previous iter); next-tile global loads are issued right after the barrier
// and consumed by ds_writes AFTER compute, so HBM latency hides under the
// 4 mi-blocks of MFMA+softmax (T14). Race check: a wave writing buf[p^1] at
// the end of iter it cannot collide with readers — every wave's last read of
// buf[p^1] was in iter it-1, before the barrier at the top of iter it.
// Barriers: 16 -> 8 per block. QK^T/softmax/PV math unchanged from r6.
__global__ __launch_bounds__(256)
void attn_kernel(const bf16_t* __restrict__ qkv, bf16_t* __restrict__ out)
{
  constexpr int VS = 72;
  constexpr int BUF = 64 * VS;
  __shared__ bf16_t Ks[2][BUF];
  __shared__ bf16_t Vt[2][BUF];
  __shared__ bf16_t Ps[4][16 * VS];

  const int h     = blockIdx.x & 15;
  const int qtile = blockIdx.x >> 4;

  const int t = threadIdx.x;
  const int wave = t >> 6, lane = t & 63;
  const int quad = lane >> 4, l15 = lane & 15;

  const int qrow0 = qtile * 256 + wave * 64;
  const int krow0 = (qtile >> 1) * 512;
  const int qcol = h * 64;
  const int kcol = 1024 + h * 64;
  const int vcol = 2048 + h * 64;

  bf16x8 qf[4][2];
#pragma unroll
  for (int mi = 0; mi < 4; mi++)
#pragma unroll
    for (int kb = 0; kb < 2; kb++)
      qf[mi][kb] = *(const bf16x8*)(qkv + (size_t)(qrow0 + mi * 16 + l15) * 3072 + qcol + kb * 32 + quad * 8);

  floatx4 o[4][4] = {};
  float plsum[4] = {};

  const float SCL = 0.125f * 1.44269504088896f;

  // staging addresses (same decomposition as r6)
  const bf16_t* kg0 = qkv + (size_t)(krow0 + (t >> 3)) * 3072 + kcol + (t & 7) * 8;
  const bf16_t* kg1 = qkv + (size_t)(krow0 + 32 + (t >> 3)) * 3072 + kcol + (t & 7) * 8;
  const bf16_t* vg0 = qkv + (size_t)(krow0 + (t & 63)) * 3072 + vcol + (t >> 6) * 8;
  const bf16_t* vg1 = qkv + (size_t)(krow0 + (t & 63)) * 3072 + vcol + ((t >> 6) + 4) * 8;
  const int kso0 = (t >> 3) * VS + (t & 7) * 8;
  const int kso1 = ((t >> 3) + 32) * VS + (t & 7) * 8;
  const int vto0 = (t >> 6) * 8 * VS + (t & 63);
  const int vto1 = ((t >> 6) + 4) * 8 * VS + (t & 63);

  // prologue: tile 0 -> regs -> buf0 (published by the it=0 barrier)
  bf16x8 kreg0 = *(const bf16x8*)kg0;
  bf16x8 kreg1 = *(const bf16x8*)kg1;
  bf16x8 vreg0 = *(const bf16x8*)vg0;
  bf16x8 vreg1 = *(const bf16x8*)vg1;
  *(bf16x8*)(Ks[0] + kso0) = kreg0;
  *(bf16x8*)(Ks[0] + kso1) = kreg1;
#pragma unroll
  for (int j = 0; j < 8; j++) { Ks[0][0] = Ks[0][0]; }  // no-op placeholder removed below
#pragma unroll
  for (int j = 0; j < 8; j++) { Vt[0][vto0 + j * VS] = vreg0[j]; Vt[0][vto1 + j * VS] = vreg1[j]; }

  for (int it = 0; it < 8; it++) {
    const int p = it & 1;
    __syncthreads();   // publishes buf[p] (prologue writes or prev-iter writes)

    if (it < 7) {      // issue next tile's loads; consumed by ds_writes below
      const size_t off = (size_t)(it + 1) * 64 * 3072;
      kreg0 = *(const bf16x8*)(kg0 + off);
      kreg1 = *(const bf16x8*)(kg1 + off);
      vreg0 = *(const bf16x8*)(vg0 + off);
      vreg1 = *(const bf16x8*)(vg1 + off);
    }

    const bf16_t* Kb = Ks[p];
    const bf16_t* Vb = Vt[p];
    bf16x8 kf[4][2], vf[4][2];
#pragma unroll
    for (int ni = 0; ni < 4; ni++)
#pragma unroll
      for (int kb = 0; kb < 2; kb++) {
        kf[ni][kb] = *(const bf16x8*)(Kb + (ni * 16 + l15) * VS + kb * 32 + quad * 8);
        vf[ni][kb] = *(const bf16x8*)(Vb + (ni * 16 + l15) * VS + kb * 32 + quad * 8);
      }

#pragma unroll
    for (int mi = 0; mi < 4; mi++) {
      floatx4 s[4] = {};
      __builtin_amdgcn_s_setprio(1);
#pragma unroll
      for (int ni = 0; ni < 4; ni++) {
        // swapped operands: D = K . Q^T = S^T ; lane&15 = q, quad*4+r = key
        s[ni] = MFMA_16x16x32_BF16(kf[ni][0], qf[mi][0], s[ni]);
        s[ni] = MFMA_16x16x32_BF16(kf[ni][1], qf[mi][1], s[ni]);
      }
      __builtin_amdgcn_s_setprio(0);
      float ps = 0.0f;
#pragma unroll
      for (int ni = 0; ni < 4; ni++) {
        bf16x4 w;
#pragma unroll
        for (int r = 0; r < 4; r++) {
          const float p2 = exp2f(s[ni][r] * SCL);
          ps += p2;
          w[r] = (bf16_t)p2;
        }
        *(bf16x4*)(Ps[wave] + l15 * VS + ni * 16 + quad * 4) = w;
      }
      plsum[mi] += ps;
      bf16x8 pf0 = *(const bf16x8*)(Ps[wave] + l15 * VS + quad * 8);
      bf16x8 pf1 = *(const bf16x8*)(Ps[wave] + l15 * VS + 32 + quad * 8);
      __builtin_amdgcn_s_setprio(1);
#pragma unroll
      for (int ni = 0; ni < 4; ni++) {
        o[mi][ni] = MFMA_16x16x32_BF16(pf0, vf[ni][0], o[mi][ni]);
        o[mi][ni] = MFMA_16x16x32_BF16(pf1, vf[ni][1], o[mi][ni]);
      }
      __builtin_amdgcn_s_setprio(0);
    }

    if (it < 7) {      // write next tile into buf[p^1]; published by next barrier
      bf16_t* Kn = Ks[p ^ 1];
      bf16_t* Vn = Vt[p ^ 1];
      *(bf16x8*)(Kn + kso0) = kreg0;
      *(bf16x8*)(Kn + kso1) = kreg1;
#pragma unroll
      for (int j = 0; j < 8; j++) { Vn[vto0 + j * VS] = vreg0[j]; Vn[vto1 + j * VS] = vreg1[j]; }
    }
  }

#pragma unroll
  for (int mi = 0; mi < 4; mi++) {
    float tot = plsum[mi];
    tot += __shfl_xor(tot, 16, 64);
    tot += __shfl_xor(tot, 32, 64);
    const float inv = 1.0f / tot;
#pragma unroll
    for (int r = 0; r < 4; r++) {
      const float invr = __shfl(inv, quad * 4 + r, 16);
      const size_t rbase = (size_t)(qrow0 + mi * 16 + quad * 4 + r) * 1024 + h * 64 + l15;
#pragma unroll
      for (int ni = 0; ni < 4; ni++)
        out[rbase + ni * 16] = (bf16_t)(o[mi][ni][r] * invr);
    }
  }
}

extern "C" void kernel_launch(void* const* d_in, const int* in_sizes, int n_in,
                              void* d_out, int out_size, void* d_ws, size_t ws_size,
                              hipStream_t stream)
{
  const float* x     = (const float*)d_in[0];   // [4,4096,1024]
  const float* w_qkv = (const float*)d_in[1];   // [3072,1024]
  const float* w_out = (const float*)d_in[2];   // [1024,1024]
  const float* b_out = (const float*)d_in[3];   // [1024]
  float* out = (float*)d_out;                   // [4,4096,1024] fp32

  const size_t WQ = (size_t)3072 * 1024, WO = (size_t)1024 * 1024;
  bf16_t* wq_b = (bf16_t*)d_ws;
  bf16_t* wo_b = wq_b + WQ;

  int rows = 16384;   // 10240 B/row of chunk buffers
  while ((size_t)rows * 10240 + (WQ + WO) * 2 > ws_size && rows > 512) rows >>= 1;
  const int nchunk = 16384 / rows;

  bf16_t* qkv_c = wo_b + WO;
  bf16_t* att_c = qkv_c + (size_t)rows * 3072;
  bf16_t* x_c   = att_c + (size_t)rows * 1024;

  f32_to_bf16_kernel<<<1536, 256, 0, stream>>>(w_qkv, wq_b, (int)(WQ / 8));
  f32_to_bf16_kernel<<<512, 256, 0, stream>>>(w_out, wo_b, (int)(WO / 8));

  for (int c = 0; c < nchunk; c++) {
    const float* xc = x + (size_t)c * rows * 1024;
    float* outc = out + (size_t)c * rows * 1024;
    // 0) x chunk -> bf16
    f32_to_bf16_kernel<<<2048, 256, 0, stream>>>(xc, x_c, rows * 128);
    // 1) QKV projection (bf16 x bf16 -> bf16): grid = 12*(rows/256), %8==0
    gemm_bt256<bf16_t, false><<<dim3((3072 / 256) * (rows / 256)), 512, 0, stream>>>(
        x_c, wq_b, nullptr, qkv_c, rows, 3072, 1024);
    // 2) blocked attention
    attn_kernel<<<dim3(16 * (rows / 256)), 256, 0, stream>>>(qkv_c, att_c);
    // 3) output projection + bias: grid = 4*(rows/256), %8==0
    gemm_bt256<float, true><<<dim3((1024 / 256) * (rows / 256)), 512, 0, stream>>>(
        att_c, wo_b, b_out, outc, rows, 1024, 1024);
  }
}